// Round 7
// baseline (164.941 us; speedup 1.0000x reference)
//
#include <hip/hip_runtime.h>
#include <hip/hip_bf16.h>
#include <stdint.h>

#define B_ 4
#define N_ 4096
#define D_ 64
#define K_ 16

// ---------------- workspace layout (float-element offsets) ----------------
static const size_t OFS_WQA1  = 0;                      // Wq@A1      [64x64]
static const size_t OFS_WKA1  = 4096;                   // Wk@A1      [64x64]
static const size_t OFS_WCOMB = 8192;                   // [c][dd] dd<64: P2@A1, dd>=64: P2   [64x128]
static const size_t OFS_C1    = 16384;                  // p2b@A1 + a1b  [64]
static const size_t OFS_QA1   = 16448;                  // x@WqA1     [B*N*64]
static const size_t OFS_KA1   = OFS_QA1 + (size_t)B_*N_*64;
static const size_t OFS_V     = OFS_KA1 + (size_t)B_*N_*64;
static const size_t OFS_IDX   = OFS_V   + (size_t)B_*N_*64;           // int [B*N*16]
static const size_t OFS_POS4  = OFS_IDX + (size_t)B_*N_*16;           // float4 [B*N] (byte%16==0)
static const size_t OFS_BF16  = OFS_POS4 + (size_t)B_*N_*4;           // ushort: wcombT[128][64], a2T[64][64] (12288 ush)
static const size_t OFS_PBF   = OFS_BF16 + 6144;                      // ushort: Wcat^T frag layout [192][64]
static const size_t OFS_WFB   = OFS_PBF + 6144;                       // ushort: Wf^T frag layout [64][64]
static const size_t OFS_APK   = OFS_WFB + 2048;                       // ushort [B*N][32]: query MFMA pack (hi/lo bf16)
static const size_t OFS_BPK   = OFS_APK + 262144;                     // ushort [B*N][32]: candidate MFMA pack

#define KNN_CAP 96

typedef __attribute__((ext_vector_type(8))) short short8;
typedef __attribute__((ext_vector_type(4))) float floatx4;

__device__ __forceinline__ unsigned short f2bf(float f) {
    __hip_bfloat16 h = __float2bfloat16(f);
    return *reinterpret_cast<unsigned short*>(&h);
}

__device__ __forceinline__ float bf2f(unsigned short u) {
    __hip_bfloat16 h = *reinterpret_cast<__hip_bfloat16*>(&u);
    return __bfloat162float(h);
}

__device__ __forceinline__ unsigned long long bsortu64(unsigned long long v, int l) {
#pragma unroll
    for (int k = 2; k <= 64; k <<= 1) {
#pragma unroll
        for (int j = k >> 1; j > 0; j >>= 1) {
            unsigned long long o = __shfl_xor(v, j, 64);
            unsigned long long mn = v < o ? v : o;
            unsigned long long mx = v < o ? o : v;
            v = ((((l & j) == 0) == ((l & k) == 0))) ? mn : mx;
        }
    }
    return v;
}

// dual interleaved bitonic sorts (two independent chains overlap latency)
__device__ __forceinline__ void bsortu64x2(unsigned long long& a, unsigned long long& b, int l) {
#pragma unroll
    for (int k = 2; k <= 64; k <<= 1) {
#pragma unroll
        for (int j = k >> 1; j > 0; j >>= 1) {
            unsigned long long oa = __shfl_xor(a, j, 64);
            unsigned long long ob = __shfl_xor(b, j, 64);
            bool up = (((l & j) == 0) == ((l & k) == 0));
            unsigned long long mna = a < oa ? a : oa, mxa = a < oa ? oa : a;
            unsigned long long mnb = b < ob ? b : ob, mxb = b < ob ? ob : b;
            a = up ? mna : mxa;
            b = up ? mnb : mxb;
        }
    }
}

// ---------------- launch 1: precompute (+bf16 weights) | pos4 + MFMA packs ----
// [0,65): WQA1/WKA1/WCOMB/C1 (+bf16 frags)  [65,81): Wv  [81,97): Wf  [97,161): pos4+packs
__global__ __launch_bounds__(256) void k_pre(
        const float* __restrict__ Wq, const float* __restrict__ Wk,
        const float* __restrict__ Wv, const float* __restrict__ Wf,
        const float* __restrict__ P2, const float* __restrict__ A1,
        const float* __restrict__ p2b, const float* __restrict__ a1b,
        const float* __restrict__ pos, float* __restrict__ ws) {
    int blk = blockIdx.x;
    unsigned short* pbf = (unsigned short*)(ws + OFS_PBF);
    if (blk < 65) {
        int i = blk * 256 + threadIdx.x;
        if (i < 4096) {
            int c = i >> 6, d = i & 63;
            float s = 0.f;
            for (int e = 0; e < 64; ++e) s = fmaf(Wq[c*64+e], A1[e*64+d], s);
            ws[OFS_WQA1 + i] = s;
            pbf[d*64 + c] = f2bf(s);
        } else if (i < 8192) {
            int j = i - 4096; int c = j >> 6, d = j & 63;
            float s = 0.f;
            for (int e = 0; e < 64; ++e) s = fmaf(Wk[c*64+e], A1[e*64+d], s);
            ws[OFS_WKA1 + j] = s;
            pbf[(64+d)*64 + c] = f2bf(s);
        } else if (i < 16384) {
            int j = i - 8192; int c = j >> 7, dd = j & 127;
            float s;
            if (dd < 64) { s = 0.f; for (int e = 0; e < 64; ++e) s = fmaf(P2[c*64+e], A1[e*64+dd], s); }
            else s = P2[c*64 + (dd - 64)];
            ws[OFS_WCOMB + j] = s;
        } else if (i < 16448) {
            int d = i - 16384;
            float s = a1b[d];
            for (int e = 0; e < 64; ++e) s = fmaf(p2b[e], A1[e*64+d], s);
            ws[OFS_C1 + d] = s;
        }
    } else if (blk < 81) {
        int i = (blk - 65) * 256 + threadIdx.x;    // 4096 elems
        int c = i >> 6, d = i & 63;
        pbf[(128+d)*64 + c] = f2bf(Wv[c*64+d]);
    } else if (blk < 97) {
        int i = (blk - 81) * 256 + threadIdx.x;    // 4096 elems
        int c = i >> 6, d = i & 63;
        ((unsigned short*)(ws + OFS_WFB))[d*64 + c] = f2bf(Wf[c*64+d]);
    } else {
        int i = (blk - 97) * 256 + threadIdx.x;    // 64 blocks -> 16384 points
        float px = pos[(size_t)i*3+0], py = pos[(size_t)i*3+1], pz = pos[(size_t)i*3+2];
        float sq = fmaf(pz, pz, fmaf(py, py, px*px));
        ((float4*)(ws + OFS_POS4))[i] = make_float4(px, py, pz, sq);

        // hi/lo bf16 split packs for MFMA distance:
        //   sum_k A[k]*B[k] ~= -2*q.p + |q|^2 + |c|^2   (error <~1e-4)
        unsigned short xh = f2bf(px), yh = f2bf(py), zh = f2bf(pz), sh = f2bf(sq);
        float xl = px - bf2f(xh), yl = py - bf2f(yh), zl = pz - bf2f(zh), sl = sq - bf2f(sh);
        unsigned short xlb = f2bf(xl), ylb = f2bf(yl), zlb = f2bf(zl), slb = f2bf(sl);
        unsigned short m2xh = f2bf(-2.f*bf2f(xh)), m2yh = f2bf(-2.f*bf2f(yh)), m2zh = f2bf(-2.f*bf2f(zh));
        unsigned short m2xl = f2bf(-2.f*xl), m2yl = f2bf(-2.f*yl), m2zl = f2bf(-2.f*zl);
        const unsigned short ONE = 0x3F80;
        union { unsigned short u[32]; uint4 v[4]; } A, Bp;
#pragma unroll
        for (int j2 = 0; j2 < 32; ++j2) { A.u[j2] = 0; Bp.u[j2] = 0; }
        A.u[0]=m2xh; A.u[1]=m2xh; A.u[2]=m2xl;
        A.u[3]=m2yh; A.u[4]=m2yh; A.u[5]=m2yl;
        A.u[6]=m2zh; A.u[7]=m2zh; A.u[8]=m2zl;
        A.u[9]=sh;   A.u[10]=slb; A.u[11]=ONE; A.u[12]=ONE;
        Bp.u[0]=xh;  Bp.u[1]=xlb; Bp.u[2]=xh;
        Bp.u[3]=yh;  Bp.u[4]=ylb; Bp.u[5]=yh;
        Bp.u[6]=zh;  Bp.u[7]=zlb; Bp.u[8]=zh;
        Bp.u[9]=ONE; Bp.u[10]=ONE; Bp.u[11]=sh; Bp.u[12]=slb;
        uint4* ap4 = (uint4*)(ws + OFS_APK);
        uint4* bp4 = (uint4*)(ws + OFS_BPK);
#pragma unroll
        for (int j2 = 0; j2 < 4; ++j2) { ap4[(size_t)i*4+j2] = A.v[j2]; bp4[(size_t)i*4+j2] = Bp.v[j2]; }
    }
}

// ---------------- launch 2 (merged): kNN + projection, block-range split ------
// Blocks [0,1024): MFMA-filtered exact kNN (dual-chain, depth-3 pipelined).
// Blocks [1024,1280): MFMA projection x[64 rows] @ Wcat[64x192], 8-wave split.
// Blocks [1280,1304): bf16 weight staging (wcombT + A2^T).
// The two roles are data-independent (both consume only k_pre outputs), so the
// projection fills CU issue slots left idle by the latency-bound kNN waves.
__device__ __forceinline__ unsigned long long knn_entry(
        const float4 q4, const float4* __restrict__ pos4b,
        const unsigned* __restrict__ s, int T, int e) {
    bool valid = e < T;
    int re = e < KNN_CAP ? e : KNN_CAP - 1;       // LDS read always in-bounds
    unsigned idxv = s[re];
    // guard: padding lanes would read uninitialized LDS -> garbage index ->
    // OOB global read -> fault. Clamp before dereferencing.
    idxv = valid ? (idxv & 4095u) : 0u;
    float4 c4 = pos4b[idxv];
    float dot = fmaf(q4.z, c4.z, fmaf(q4.y, c4.y, q4.x*c4.x));
    float d = fmaxf(fmaf(-2.f, dot, q4.w + c4.w), 0.f);
    unsigned long long pk = ((unsigned long long)__float_as_uint(d) << 32) | idxv;
    return valid ? pk : ~0ull;
}

__device__ __forceinline__ unsigned long long knn_merge_rest1(
        unsigned long long best, int l, const float4 q4,
        const float4* __restrict__ pos4b, const unsigned* __restrict__ s, int T) {
    for (int base = 64; base < T; base += 64) {
        unsigned long long w2 = knn_entry(q4, pos4b, s, T, base + l);
        w2 = bsortu64(w2, l);
        unsigned long long bb = __shfl(w2, (l - 16) & 63, 64);
        unsigned long long nv = (l < 16) ? best : ((l < 32) ? bb : ~0ull);
        best = bsortu64(nv, l);
    }
    return best;
}

__global__ __launch_bounds__(512, 4) void k_knn(const float* __restrict__ x,
                                                const float* __restrict__ A2,
                                                float* __restrict__ ws) {
    __shared__ __align__(16) unsigned char smem[36864];   // overlaid arena
    const int bid = (int)blockIdx.x;
    const int t = threadIdx.x;

    if (bid >= 1024) {
        // ================= projection role =================
        if (bid >= 1280) {
            // bf16 weight staging: 24 blocks x 512 -> 12288 elems
            int i = (bid - 1280) * 512 + t;
            unsigned short* wbf = (unsigned short*)(ws + OFS_BF16);
            if (i < 8192) {
                int c = i >> 7, dd = i & 127;
                wbf[dd*64 + c] = f2bf(ws[OFS_WCOMB + i]);
            } else {
                int j = i - 8192; int e = j >> 6, d = j & 63;
                wbf[8192 + d*64 + e] = f2bf(A2[j]);
            }
            return;
        }
        unsigned short* xT  = (unsigned short*)smem;           // [64][72]
        unsigned short* wTs = (unsigned short*)(smem + 9216);  // [192][72]
        const unsigned short* pbf = (const unsigned short*)(ws + OFS_PBF);
        const int g0 = (bid - 1024) * 64;

#pragma unroll
        for (int k = 0; k < 3; ++k) {
            int id  = t + 512*k;
            int row = id >> 3, cir = id & 7;
            uint4 vv = *(const uint4*)(pbf + row*64 + cir*8);
            *(uint4*)&wTs[row*72 + cir*8] = vv;
        }
        {
            int r = t >> 3, qd = t & 7;
            const float* src = x + (size_t)(g0 + r)*64 + qd*8;
            unsigned short hb[8];
#pragma unroll
            for (int u = 0; u < 8; ++u) hb[u] = f2bf(src[u]);
            *(uint4*)&xT[r*72 + qd*8] = *(uint4*)&hb[0];
        }
        __syncthreads();

        const int w = t >> 6, l = t & 63, lr = l & 15, q = l >> 4;
        const int w4 = w & 3, jh = w >> 2;     // row tile / column half
        floatx4 acc[6];
#pragma unroll
        for (int j = 0; j < 6; ++j) acc[j] = (floatx4){0.f, 0.f, 0.f, 0.f};
#pragma unroll
        for (int kb = 0; kb < 2; ++kb) {
            short8 a = *(const short8*)&xT[(16*w4 + lr)*72 + 32*kb + 8*q];
#pragma unroll
            for (int j = 0; j < 6; ++j) {
                int jj = jh*6 + j;
                short8 bfr = *(const short8*)&wTs[(16*jj + lr)*72 + 32*kb + 8*q];
                acc[j] = __builtin_amdgcn_mfma_f32_16x16x32_bf16(a, bfr, acc[j], 0, 0, 0);
            }
        }
        float* qA1 = ws + OFS_QA1;
        float* kA1 = ws + OFS_KA1;
        float* vws = ws + OFS_V;
#pragma unroll
        for (int j = 0; j < 6; ++j) {
            int col = 16*(jh*6 + j) + lr;
            float* dst = (col < 64) ? qA1 : (col < 128 ? kA1 : vws);
            int c2 = col & 63;
#pragma unroll
            for (int r = 0; r < 4; ++r) {
                int grow = g0 + 16*w4 + 4*q + r;
                dst[(size_t)grow*64 + c2] = acc[j][r];
            }
        }
        return;
    }

    // ================= kNN role =================
    // 8 waves = 1 query-group (16 queries) x 8 candidate regions (512 each).
    // Sweep1: dual-chain depth-3 pipelined per-lane (min1,min2) (med3 update);
    // 256-thread reduce -> global tau = rank-8 of 16 lane-min2s (>=16 witnesses).
    // Sweep2: same pipeline + rare-path LDS-atomic compaction (E~25 / query).
    // Pass3: exact fp32 distances + bitonic top-16.
    float2* minbuf   = (float2*)smem;                          // [16*16*9]
    unsigned* surv   = (unsigned*)(smem + 18432);              // [16*KNN_CAP]
    int* scnt        = (int*)(smem + 18432 + 6144);            // [16]
    float* taubuf    = (float*)(smem + 18432 + 6144 + 64);     // [16]
    const unsigned short* apk = (const unsigned short*)(ws + OFS_APK);
    const unsigned short* bpk = (const unsigned short*)(ws + OFS_BPK);
    const int w = t >> 6, l = t & 63;             // w = candidate region (0..7)
    const int lr = l & 15, hi4 = l >> 4;
    const int g0 = bid * 16;                      // 1024 blocks -> 16384 queries
    const int b  = g0 >> 12;

    if (t < 16) scnt[t] = 0;

    // A-frag: row (query) = l&15, k = 8*(l>>4)+j  (same layout as projection)
    short8 afrag = *(const short8*)(apk + (size_t)(g0 + lr)*32 + 8*hi4);
    const unsigned short* bbase = bpk + (size_t)(b*4096 + w*512 + lr)*32 + 8*hi4;
    const floatx4 z4 = {0.f, 0.f, 0.f, 0.f};

    // ---- sweep 1: dual-chain depth-3 pipelined min1/min2 ----
    float run1[4], run2[4];
#pragma unroll
    for (int r = 0; r < 4; ++r) { run1[r] = 1e30f; run2[r] = 1e30f; }
    {
        short8 cA0 = *(const short8*)(bbase);            // chain A: tiles 0..15
        short8 cA1 = *(const short8*)(bbase + 512);
        short8 cB0 = *(const short8*)(bbase + 16*512);   // chain B: tiles 16..31
        short8 cB1 = *(const short8*)(bbase + 17*512);
#pragma unroll
        for (int g = 0; g < 16; ++g) {
            const int gn = (g + 2) & 15;     // wraps: 4 redundant loads at end
            short8 nA = *(const short8*)(bbase + gn*512);
            short8 nB = *(const short8*)(bbase + (16+gn)*512);
            floatx4 aA = __builtin_amdgcn_mfma_f32_16x16x32_bf16(afrag, cA0, z4, 0, 0, 0);
            floatx4 aB = __builtin_amdgcn_mfma_f32_16x16x32_bf16(afrag, cB0, z4, 0, 0, 0);
#pragma unroll
            for (int r = 0; r < 4; ++r) {
                // run1 <= run2 invariant -> median(a,run1,run2) == min(max(a,run1),run2)
                run2[r] = __builtin_amdgcn_fmed3f(aA[r], run1[r], run2[r]);
                run1[r] = fminf(run1[r], aA[r]);
                run2[r] = __builtin_amdgcn_fmed3f(aB[r], run1[r], run2[r]);
                run1[r] = fminf(run1[r], aB[r]);
            }
            cA0 = cA1; cA1 = nA;
            cB0 = cB1; cB1 = nB;
        }
    }
#pragma unroll
    for (int r = 0; r < 4; ++r)
        minbuf[((4*hi4 + r)*16 + lr)*9 + w] = make_float2(run1[r], run2[r]);
    __syncthreads();

    // ---- reduce: global (min1,min2) per (query, col-lane); tau = rank-8 ----
    if (t < 256) {
        int q = t >> 4, cl = t & 15;
        float m1 = 1e30f, m2 = 1e30f;
#pragma unroll
        for (int wv = 0; wv < 8; ++wv) {
            float2 p = minbuf[(q*16 + cl)*9 + wv];
            float hi = fmaxf(m1, p.x);
            m1 = fminf(m1, p.x);
            m2 = fminf(fminf(m2, p.y), hi);
        }
        float v = m2;
#pragma unroll
        for (int k = 2; k <= 16; k <<= 1) {
#pragma unroll
            for (int j = k >> 1; j > 0; j >>= 1) {
                float o = __shfl_xor(v, j, 64);
                bool up = (((cl & j) == 0) == ((cl & k) == 0));
                v = up ? fminf(v, o) : fmaxf(v, o);
            }
        }
        if (cl == 7) taubuf[q] = v + 1e-3f;       // margin >> 2*pack-error
    }
    __syncthreads();

    float tau[4];
#pragma unroll
    for (int r = 0; r < 4; ++r) tau[r] = taubuf[4*hi4 + r];

    // ---- sweep 2: same pipeline + rare-path atomic compaction ----
    const unsigned cand0 = (unsigned)(w*512 + lr);
    const int qb0 = 4*hi4;
    {
        short8 cA0 = *(const short8*)(bbase);
        short8 cA1 = *(const short8*)(bbase + 512);
        short8 cB0 = *(const short8*)(bbase + 16*512);
        short8 cB1 = *(const short8*)(bbase + 17*512);
#pragma unroll
        for (int g = 0; g < 16; ++g) {
            const int gn = (g + 2) & 15;
            short8 nA = *(const short8*)(bbase + gn*512);
            short8 nB = *(const short8*)(bbase + (16+gn)*512);
            floatx4 aA = __builtin_amdgcn_mfma_f32_16x16x32_bf16(afrag, cA0, z4, 0, 0, 0);
            floatx4 aB = __builtin_amdgcn_mfma_f32_16x16x32_bf16(afrag, cB0, z4, 0, 0, 0);
            unsigned cidA = cand0 + (unsigned)(g*16);
            unsigned cidB = cand0 + (unsigned)((16+g)*16);
#pragma unroll
            for (int r = 0; r < 4; ++r) {
                if (aA[r] <= tau[r]) {
                    int p = atomicAdd(&scnt[qb0+r], 1);
                    if (p < KNN_CAP) surv[(qb0+r)*KNN_CAP + p] = cidA;
                }
                if (aB[r] <= tau[r]) {
                    int p = atomicAdd(&scnt[qb0+r], 1);
                    if (p < KNN_CAP) surv[(qb0+r)*KNN_CAP + p] = cidB;
                }
            }
            cA0 = cA1; cA1 = nA;
            cB0 = cB1; cB1 = nB;
        }
    }
    __syncthreads();

    // ---- pass 3: exact fp32 distances for survivors, top-16 select ----
    const float4* pos4g = (const float4*)(ws + OFS_POS4);
    const float4* pos4b = pos4g + (size_t)b * N_;
    int* idx = (int*)(ws + OFS_IDX);
    int qa = 2*w, qb = 2*w + 1;                   // block-local 0..15
    int Ta = scnt[qa]; Ta = Ta < KNN_CAP ? Ta : KNN_CAP;
    int Tb = scnt[qb]; Tb = Tb < KNN_CAP ? Tb : KNN_CAP;
    const unsigned* sa = surv + qa*KNN_CAP;
    const unsigned* sb = surv + qb*KNN_CAP;
    float4 q4a = pos4g[g0 + qa];
    float4 q4b = pos4g[g0 + qb];
    unsigned long long pk0 = knn_entry(q4a, pos4b, sa, Ta, l);
    unsigned long long pk1 = knn_entry(q4b, pos4b, sb, Tb, l);
    bsortu64x2(pk0, pk1, l);
    if (Ta > 64) pk0 = knn_merge_rest1(pk0, l, q4a, pos4b, sa, Ta);
    if (Tb > 64) pk1 = knn_merge_rest1(pk1, l, q4b, pos4b, sb, Tb);
    if (l < 16) {
        idx[(size_t)(g0 + qa)*16 + l] = (int)(pk0 & 0xFFFu);
        idx[(size_t)(g0 + qb)*16 + l] = (int)(pk1 & 0xFFFu);
    }
}

// ---------------- launch 4: fused per-neighbor MLPs + softmax + agg + out ------
// R11 structure + MFMA stage F (R13).
__global__ __launch_bounds__(256) void k_attn(
    const float* __restrict__ x, const float* __restrict__ pos,
    const float* __restrict__ P1, const float* __restrict__ p1b,
    const float* __restrict__ p2b, const float* __restrict__ a2b,
    const float* __restrict__ bff, const float* __restrict__ ws,
    float* __restrict__ out) {

    __shared__ unsigned short wT[128*72];      // wcombT fragments, stride 72
    __shared__ unsigned short a2T[64*72];      // A2^T fragments, stride 72
    __shared__ unsigned short abuf[128*72];    // h1 / h2 / agg, stride 72
    __shared__ float relb[128*4];
    __shared__ int   mrow[128];

    const int t  = threadIdx.x;
    const int g0 = blockIdx.x * 8;
    const int b  = g0 >> 12;
    const float* qA1 = ws + OFS_QA1;
    const float* kA1 = ws + OFS_KA1;
    const float* vws = ws + OFS_V;
    const float* c1  = ws + OFS_C1;
    const int* idx = (const int*)(ws + OFS_IDX);
    const unsigned short* wbf = (const unsigned short*)(ws + OFS_BF16);
    const unsigned short* wfb = (const unsigned short*)(ws + OFS_WFB);

#pragma unroll
    for (int k = 0; k < 6; ++k) {
        int id  = t + 256*k;
        int row = id >> 3, cir = id & 7;
        uint4 vv = *(const uint4*)(wbf + row*64 + cir*8);
        if (row < 128) *(uint4*)&wT[row*72 + cir*8] = vv;
        else           *(uint4*)&a2T[(row-128)*72 + cir*8] = vv;
    }

    if (t < 128) {
        int p = t >> 4, k = t & 15;
        int ng = g0 + p;
        int m  = idx[(size_t)ng*16 + k];
        int mg = b * N_ + m;
        mrow[t] = mg;
        relb[t*4+0] = pos[(size_t)ng*3+0] - pos[(size_t)mg*3+0];
        relb[t*4+1] = pos[(size_t)ng*3+1] - pos[(size_t)mg*3+1];
        relb[t*4+2] = pos[(size_t)ng*3+2] - pos[(size_t)mg*3+2];
    }
    __syncthreads();

    const int w = t >> 6, l = t & 63, lr = l & 15, q = l >> 4;

    // ---- prefetch kA1 gathers + (qA1+c1) — hidden behind h1-MLP and MFMA1 ----
    float kpre[2][4][4];
    float qpre[2][4];
#pragma unroll
    for (int i = 0; i < 2; ++i) {
        int ng = g0 + 2*w + i;
#pragma unroll
        for (int j = 0; j < 4; ++j) {
            int col = 16*j + lr;
            qpre[i][j] = qA1[(size_t)ng*64 + col] + c1[col];
#pragma unroll
            for (int r = 0; r < 4; ++r) {
                int row = 32*w + 16*i + 4*q + r;
                kpre[i][j][r] = kA1[(size_t)mrow[row]*64 + col];
            }
        }
    }

    // ---- h1 = relu(rel @ P1 + p1b) -> abuf (bf16) ----
    {
        int d = t & 63, r0 = t >> 6;
        float w0 = P1[d], w1 = P1[64+d], w2 = P1[128+d], bb = p1b[d];
#pragma unroll
        for (int jj = 0; jj < 32; ++jj) {
            int r = r0 + jj*4;
            float h = fmaf(relb[r*4+2], w2, fmaf(relb[r*4+1], w1, fmaf(relb[r*4+0], w0, bb)));
            abuf[r*72 + d] = f2bf(fmaxf(h, 0.f));
        }
    }
    __syncthreads();

    // ---- MFMA1: h1[128x64] @ [P2A1 | P2] ----
    floatx4 acc1[2][8];
#pragma unroll
    for (int i = 0; i < 2; ++i)
#pragma unroll
        for (int j = 0; j < 8; ++j) acc1[i][j] = (floatx4){0.f, 0.f, 0.f, 0.f};
#pragma unroll
    for (int kb = 0; kb < 2; ++kb) {
        short8 a0 = *(const short8*)&abuf[(32*w      + lr)*72 + 32*kb + 8*q];
        short8 a1 = *(const short8*)&abuf[(32*w + 16 + lr)*72 + 32*kb + 8*q];
#pragma unroll
        for (int j = 0; j < 8; ++j) {
            short8 bfr = *(const short8*)&wT[(16*j + lr)*72 + 32*kb + 8*q];
            acc1[0][j] = __builtin_amdgcn_mfma_f32_16x16x32_bf16(a0, bfr, acc1[0][j], 0, 0, 0);
            acc1[1][j] = __builtin_amdgcn_mfma_f32_16x16x32_bf16(a1, bfr, acc1[1][j], 0, 0, 0);
        }
    }
    __syncthreads();

    // ---- epilogue1: t1 = acc + (qA1[n]+c1) - kA1[m], h2 = relu -> abuf ----
#pragma unroll
    for (int i = 0; i < 2; ++i) {
#pragma unroll
        for (int j = 0; j < 4; ++j) {
            int col = 16*j + lr;
            float qv = qpre[i][j];
#pragma unroll
            for (int r = 0; r < 4; ++r) {
                int row = 32*w + 16*i + 4*q + r;
                float t1 = acc1[i][j][r] + qv - kpre[i][j][r];
                abuf[row*72 + col] = f2bf(fmaxf(t1, 0.f));
            }
        }
    }

    // ---- prefetch v gathers + Wf^T frags — hidden behind MFMA2+softmax ----
    float vpre[2][4][4];
#pragma unroll
    for (int i = 0; i < 2; ++i)
#pragma unroll
        for (int j = 0; j < 4; ++j) {
            int col = 16*j + lr;
#pragma unroll
            for (int r = 0; r < 4; ++r) {
                int row = 32*w + 16*i + 4*q + r;
                vpre[i][j][r] = vws[(size_t)mrow[row]*64 + col];
            }
        }
    short8 wffrag[2];
#pragma unroll
    for (int kb = 0; kb < 2; ++kb)
        wffrag[kb] = *(const short8*)&wfb[(16*w + lr)*64 + 32*kb + 8*q];
    __syncthreads();

    // ---- MFMA2: h2 @ A2 ----
    floatx4 acc2[2][4];
#pragma unroll
    for (int i = 0; i < 2; ++i)
#pragma unroll
        for (int j = 0; j < 4; ++j) acc2[i][j] = (floatx4){0.f, 0.f, 0.f, 0.f};
#pragma unroll
    for (int kb = 0; kb < 2; ++kb) {
        short8 a0 = *(const short8*)&abuf[(32*w      + lr)*72 + 32*kb + 8*q];
        short8 a1 = *(const short8*)&abuf[(32*w + 16 + lr)*72 + 32*kb + 8*q];
#pragma unroll
        for (int j = 0; j < 4; ++j) {
            short8 bfr = *(const short8*)&a2T[(16*j + lr)*72 + 32*kb + 8*q];
            acc2[0][j] = __builtin_amdgcn_mfma_f32_16x16x32_bf16(a0, bfr, acc2[0][j], 0, 0, 0);
            acc2[1][j] = __builtin_amdgcn_mfma_f32_16x16x32_bf16(a1, bfr, acc2[1][j], 0, 0, 0);
        }
    }
    __syncthreads();   // all waves done reading abuf (h2) before agg overwrites

    // ---- stage E: softmax over K=16, aggregate; agg -> abuf rows 0..7 (bf16) ----
#pragma unroll
    for (int i = 0; i < 2; ++i) {
#pragma unroll
        for (int j = 0; j < 4; ++j) {
            int col = 16*j + lr;
            float a2bv = a2b[col], p2bv = p2b[col];
            float L[4];
#pragma unroll
            for (int r = 0; r < 4; ++r) L[r] = acc2[i][j][r] + a2bv;
            float mx = fmaxf(fmaxf(L[0], L[1]), fmaxf(L[2], L[3]));
            mx = fmaxf(mx, __shfl_xor(mx, 16, 64));
            mx = fmaxf(mx, __shfl_xor(mx, 32, 64));
            float ssum = 0.f, part = 0.f;
#pragma unroll
            for (int r = 0; r < 4; ++r) {
                float e = __expf((L[r] - mx) * 0.125f);
                ssum += e;
                float wv = vpre[i][j][r] + (acc1[i][4+j][r] + p2bv);
                part = fmaf(e, wv, part);
            }
            ssum += __shfl_xor(ssum, 16, 64);
            ssum += __shfl_xor(ssum, 32, 64);
            part += __shfl_xor(part, 16, 64);
            part += __shfl_xor(part, 32, 64);
            float agg = part / ssum;
            if (q == 0) abuf[(2*w + i)*72 + col] = f2bf(agg);
        }
    }
    __syncthreads();

    // ---- stage F: out = agg @ Wf + bf + x  (MFMA) ----
    {
        floatx4 accF = (floatx4){0.f, 0.f, 0.f, 0.f};
#pragma unroll
        for (int kb = 0; kb < 2; ++kb) {
            short8 afr = *(const short8*)&abuf[lr*72 + 32*kb + 8*q];
            accF = __builtin_amdgcn_mfma_f32_16x16x32_bf16(afr, wffrag[kb], accF, 0, 0, 0);
        }
        if (q < 2) {
            int col = 16*w + lr;
            float bv = bff[col];
#pragma unroll
            for (int r = 0; r < 4; ++r) {
                int g = g0 + 4*q + r;
                out[(size_t)g*64 + col] = accF[r] + bv + x[(size_t)g*64 + col];
            }
        }
    }
}

// ---------------- launch ----------------
extern "C" void kernel_launch(void* const* d_in, const int* in_sizes, int n_in,
                              void* d_out, int out_size, void* d_ws, size_t ws_size,
                              hipStream_t stream) {
    const float* x   = (const float*)d_in[0];
    const float* pos = (const float*)d_in[1];
    const float* Wq  = (const float*)d_in[2];
    const float* Wk  = (const float*)d_in[3];
    const float* Wv  = (const float*)d_in[4];
    const float* P1  = (const float*)d_in[5];
    const float* p1b = (const float*)d_in[6];
    const float* P2  = (const float*)d_in[7];
    const float* p2b = (const float*)d_in[8];
    const float* A1  = (const float*)d_in[9];
    const float* a1b = (const float*)d_in[10];
    const float* A2  = (const float*)d_in[11];
    const float* a2b = (const float*)d_in[12];
    const float* Wf  = (const float*)d_in[13];
    const float* bf  = (const float*)d_in[14];
    float* out = (float*)d_out;
    float* ws  = (float*)d_ws;

    hipLaunchKernelGGL(k_pre,   dim3(161),  dim3(256), 0, stream,
                       Wq, Wk, Wv, Wf, P2, A1, p2b, a1b, pos, ws);
    hipLaunchKernelGGL(k_knn,   dim3(1304), dim3(512), 0, stream, x, A2, ws);
    hipLaunchKernelGGL(k_attn,  dim3(2048), dim3(256), 0, stream,
                       x, pos, P1, p1b, p2b, a2b, bf, ws, out);
}

// Round 8
// 164.371 us; speedup vs baseline: 1.0035x; 1.0035x over previous
//
#include <hip/hip_runtime.h>
#include <hip/hip_bf16.h>
#include <stdint.h>

#define B_ 4
#define N_ 4096
#define D_ 64
#define K_ 16

// ---------------- workspace layout (float-element offsets) ----------------
static const size_t OFS_WQA1  = 0;                      // Wq@A1      [64x64]
static const size_t OFS_WKA1  = 4096;                   // Wk@A1      [64x64]
static const size_t OFS_WCOMB = 8192;                   // [c][dd] dd<64: P2@A1, dd>=64: P2   [64x128]
static const size_t OFS_C1    = 16384;                  // p2b@A1 + a1b  [64]
static const size_t OFS_QA1   = 16448;                  // x@WqA1     [B*N*64]
static const size_t OFS_KA1   = OFS_QA1 + (size_t)B_*N_*64;
static const size_t OFS_V     = OFS_KA1 + (size_t)B_*N_*64;
static const size_t OFS_IDX   = OFS_V   + (size_t)B_*N_*64;           // int [B*N*16]
static const size_t OFS_POS4  = OFS_IDX + (size_t)B_*N_*16;           // float4 [B*N] (byte%16==0)
static const size_t OFS_BF16  = OFS_POS4 + (size_t)B_*N_*4;           // ushort: wcombT[128][64], a2T[64][64] (12288 ush)
static const size_t OFS_PBF   = OFS_BF16 + 6144;                      // ushort: Wcat^T frag layout [192][64]
static const size_t OFS_WFB   = OFS_PBF + 6144;                       // ushort: Wf^T frag layout [64][64]
static const size_t OFS_APK   = OFS_WFB + 2048;                       // ushort [B*N][32]: query MFMA pack (hi/lo bf16)
static const size_t OFS_BPK   = OFS_APK + 262144;                     // ushort [B*N][32]: candidate MFMA pack

#define KNN_CAP 96

typedef __attribute__((ext_vector_type(8))) short short8;
typedef __attribute__((ext_vector_type(4))) float floatx4;

__device__ __forceinline__ unsigned short f2bf(float f) {
    __hip_bfloat16 h = __float2bfloat16(f);
    return *reinterpret_cast<unsigned short*>(&h);
}

__device__ __forceinline__ float bf2f(unsigned short u) {
    __hip_bfloat16 h = *reinterpret_cast<__hip_bfloat16*>(&u);
    return __bfloat162float(h);
}

__device__ __forceinline__ unsigned long long bsortu64(unsigned long long v, int l) {
#pragma unroll
    for (int k = 2; k <= 64; k <<= 1) {
#pragma unroll
        for (int j = k >> 1; j > 0; j >>= 1) {
            unsigned long long o = __shfl_xor(v, j, 64);
            unsigned long long mn = v < o ? v : o;
            unsigned long long mx = v < o ? o : v;
            v = ((((l & j) == 0) == ((l & k) == 0))) ? mn : mx;
        }
    }
    return v;
}

// dual interleaved bitonic sorts (two independent chains overlap latency)
__device__ __forceinline__ void bsortu64x2(unsigned long long& a, unsigned long long& b, int l) {
#pragma unroll
    for (int k = 2; k <= 64; k <<= 1) {
#pragma unroll
        for (int j = k >> 1; j > 0; j >>= 1) {
            unsigned long long oa = __shfl_xor(a, j, 64);
            unsigned long long ob = __shfl_xor(b, j, 64);
            bool up = (((l & j) == 0) == ((l & k) == 0));
            unsigned long long mna = a < oa ? a : oa, mxa = a < oa ? oa : a;
            unsigned long long mnb = b < ob ? b : ob, mxb = b < ob ? ob : b;
            a = up ? mna : mxa;
            b = up ? mnb : mxb;
        }
    }
}

// ---------------- launch 1: precompute (+bf16 weights) | pos4 + MFMA packs ----
// [0,65): WQA1/WKA1/WCOMB/C1 (+bf16 frags) — A1 staged in LDS (the 64-FMA
// accumulator chains otherwise serialize on L2-latency A1 loads)
// [65,81): Wv  [81,97): Wf  [97,161): pos4+packs
__global__ __launch_bounds__(256) void k_pre(
        const float* __restrict__ Wq, const float* __restrict__ Wk,
        const float* __restrict__ Wv, const float* __restrict__ Wf,
        const float* __restrict__ P2, const float* __restrict__ A1,
        const float* __restrict__ p2b, const float* __restrict__ a1b,
        const float* __restrict__ pos, float* __restrict__ ws) {
    __shared__ float a1s[4096];                // A1 [64][64], row-major
    int blk = blockIdx.x;
    unsigned short* pbf = (unsigned short*)(ws + OFS_PBF);
    if (blk < 65) {
        {
            const float4* a4 = (const float4*)A1;
            float4* s4 = (float4*)a1s;
#pragma unroll
            for (int k = 0; k < 4; ++k) s4[threadIdx.x + 256*k] = a4[threadIdx.x + 256*k];
        }
        __syncthreads();
        int i = blk * 256 + threadIdx.x;
        if (i < 4096) {
            int c = i >> 6, d = i & 63;
            float s = 0.f;
#pragma unroll
            for (int e = 0; e < 64; ++e) s = fmaf(Wq[c*64+e], a1s[e*64+d], s);
            ws[OFS_WQA1 + i] = s;
            pbf[d*64 + c] = f2bf(s);
        } else if (i < 8192) {
            int j = i - 4096; int c = j >> 6, d = j & 63;
            float s = 0.f;
#pragma unroll
            for (int e = 0; e < 64; ++e) s = fmaf(Wk[c*64+e], a1s[e*64+d], s);
            ws[OFS_WKA1 + j] = s;
            pbf[(64+d)*64 + c] = f2bf(s);
        } else if (i < 16384) {
            int j = i - 8192; int c = j >> 7, dd = j & 127;
            float s;
            if (dd < 64) {
                s = 0.f;
#pragma unroll
                for (int e = 0; e < 64; ++e) s = fmaf(P2[c*64+e], a1s[e*64+dd], s);
            }
            else s = P2[c*64 + (dd - 64)];
            ws[OFS_WCOMB + j] = s;
        } else if (i < 16448) {
            int d = i - 16384;
            float s = a1b[d];
#pragma unroll
            for (int e = 0; e < 64; ++e) s = fmaf(p2b[e], a1s[e*64+d], s);
            ws[OFS_C1 + d] = s;
        }
    } else if (blk < 81) {
        int i = (blk - 65) * 256 + threadIdx.x;    // 4096 elems
        int c = i >> 6, d = i & 63;
        pbf[(128+d)*64 + c] = f2bf(Wv[c*64+d]);
    } else if (blk < 97) {
        int i = (blk - 81) * 256 + threadIdx.x;    // 4096 elems
        int c = i >> 6, d = i & 63;
        ((unsigned short*)(ws + OFS_WFB))[d*64 + c] = f2bf(Wf[c*64+d]);
    } else {
        int i = (blk - 97) * 256 + threadIdx.x;    // 64 blocks -> 16384 points
        float px = pos[(size_t)i*3+0], py = pos[(size_t)i*3+1], pz = pos[(size_t)i*3+2];
        float sq = fmaf(pz, pz, fmaf(py, py, px*px));
        ((float4*)(ws + OFS_POS4))[i] = make_float4(px, py, pz, sq);

        // hi/lo bf16 split packs for MFMA distance:
        //   sum_k A[k]*B[k] ~= -2*q.p + |q|^2 + |c|^2   (error <~1e-4)
        unsigned short xh = f2bf(px), yh = f2bf(py), zh = f2bf(pz), sh = f2bf(sq);
        float xl = px - bf2f(xh), yl = py - bf2f(yh), zl = pz - bf2f(zh), sl = sq - bf2f(sh);
        unsigned short xlb = f2bf(xl), ylb = f2bf(yl), zlb = f2bf(zl), slb = f2bf(sl);
        unsigned short m2xh = f2bf(-2.f*bf2f(xh)), m2yh = f2bf(-2.f*bf2f(yh)), m2zh = f2bf(-2.f*bf2f(zh));
        unsigned short m2xl = f2bf(-2.f*xl), m2yl = f2bf(-2.f*yl), m2zl = f2bf(-2.f*zl);
        const unsigned short ONE = 0x3F80;
        union { unsigned short u[32]; uint4 v[4]; } A, Bp;
#pragma unroll
        for (int j2 = 0; j2 < 32; ++j2) { A.u[j2] = 0; Bp.u[j2] = 0; }
        A.u[0]=m2xh; A.u[1]=m2xh; A.u[2]=m2xl;
        A.u[3]=m2yh; A.u[4]=m2yh; A.u[5]=m2yl;
        A.u[6]=m2zh; A.u[7]=m2zh; A.u[8]=m2zl;
        A.u[9]=sh;   A.u[10]=slb; A.u[11]=ONE; A.u[12]=ONE;
        Bp.u[0]=xh;  Bp.u[1]=xlb; Bp.u[2]=xh;
        Bp.u[3]=yh;  Bp.u[4]=ylb; Bp.u[5]=yh;
        Bp.u[6]=zh;  Bp.u[7]=zlb; Bp.u[8]=zh;
        Bp.u[9]=ONE; Bp.u[10]=ONE; Bp.u[11]=sh; Bp.u[12]=slb;
        uint4* ap4 = (uint4*)(ws + OFS_APK);
        uint4* bp4 = (uint4*)(ws + OFS_BPK);
#pragma unroll
        for (int j2 = 0; j2 < 4; ++j2) { ap4[(size_t)i*4+j2] = A.v[j2]; bp4[(size_t)i*4+j2] = Bp.v[j2]; }
    }
}

// ---------------- launch 2 (merged): kNN + projection, block-range split ------
// Blocks [0,1024): MFMA-filtered exact kNN (dual-chain, depth-3 pipelined).
// Blocks [1024,1280): MFMA projection x[64 rows] @ Wcat[64x192], 8-wave split.
// Blocks [1280,1304): bf16 weight staging (wcombT + A2^T).
// The two roles are data-independent (both consume only k_pre outputs), so the
// projection fills CU issue slots left idle by the latency-bound kNN waves.
__device__ __forceinline__ unsigned long long knn_entry(
        const float4 q4, const float4* __restrict__ pos4b,
        const unsigned* __restrict__ s, int T, int e) {
    bool valid = e < T;
    int re = e < KNN_CAP ? e : KNN_CAP - 1;       // LDS read always in-bounds
    unsigned idxv = s[re];
    // guard: padding lanes would read uninitialized LDS -> garbage index ->
    // OOB global read -> fault. Clamp before dereferencing.
    idxv = valid ? (idxv & 4095u) : 0u;
    float4 c4 = pos4b[idxv];
    float dot = fmaf(q4.z, c4.z, fmaf(q4.y, c4.y, q4.x*c4.x));
    float d = fmaxf(fmaf(-2.f, dot, q4.w + c4.w), 0.f);
    unsigned long long pk = ((unsigned long long)__float_as_uint(d) << 32) | idxv;
    return valid ? pk : ~0ull;
}

__device__ __forceinline__ unsigned long long knn_merge_rest1(
        unsigned long long best, int l, const float4 q4,
        const float4* __restrict__ pos4b, const unsigned* __restrict__ s, int T) {
    for (int base = 64; base < T; base += 64) {
        unsigned long long w2 = knn_entry(q4, pos4b, s, T, base + l);
        w2 = bsortu64(w2, l);
        unsigned long long bb = __shfl(w2, (l - 16) & 63, 64);
        unsigned long long nv = (l < 16) ? best : ((l < 32) ? bb : ~0ull);
        best = bsortu64(nv, l);
    }
    return best;
}

__global__ __launch_bounds__(512, 4) void k_knn(const float* __restrict__ x,
                                                const float* __restrict__ A2,
                                                float* __restrict__ ws) {
    __shared__ __align__(16) unsigned char smem[36864];   // overlaid arena
    const int bid = (int)blockIdx.x;
    const int t = threadIdx.x;

    if (bid >= 1024) {
        // ================= projection role =================
        if (bid >= 1280) {
            // bf16 weight staging: 24 blocks x 512 -> 12288 elems
            int i = (bid - 1280) * 512 + t;
            unsigned short* wbf = (unsigned short*)(ws + OFS_BF16);
            if (i < 8192) {
                int c = i >> 7, dd = i & 127;
                wbf[dd*64 + c] = f2bf(ws[OFS_WCOMB + i]);
            } else {
                int j = i - 8192; int e = j >> 6, d = j & 63;
                wbf[8192 + d*64 + e] = f2bf(A2[j]);
            }
            return;
        }
        unsigned short* xT  = (unsigned short*)smem;           // [64][72]
        unsigned short* wTs = (unsigned short*)(smem + 9216);  // [192][72]
        const unsigned short* pbf = (const unsigned short*)(ws + OFS_PBF);
        const int g0 = (bid - 1024) * 64;

#pragma unroll
        for (int k = 0; k < 3; ++k) {
            int id  = t + 512*k;
            int row = id >> 3, cir = id & 7;
            uint4 vv = *(const uint4*)(pbf + row*64 + cir*8);
            *(uint4*)&wTs[row*72 + cir*8] = vv;
        }
        {
            int r = t >> 3, qd = t & 7;
            const float* src = x + (size_t)(g0 + r)*64 + qd*8;
            unsigned short hb[8];
#pragma unroll
            for (int u = 0; u < 8; ++u) hb[u] = f2bf(src[u]);
            *(uint4*)&xT[r*72 + qd*8] = *(uint4*)&hb[0];
        }
        __syncthreads();

        const int w = t >> 6, l = t & 63, lr = l & 15, q = l >> 4;
        const int w4 = w & 3, jh = w >> 2;     // row tile / column half
        floatx4 acc[6];
#pragma unroll
        for (int j = 0; j < 6; ++j) acc[j] = (floatx4){0.f, 0.f, 0.f, 0.f};
#pragma unroll
        for (int kb = 0; kb < 2; ++kb) {
            short8 a = *(const short8*)&xT[(16*w4 + lr)*72 + 32*kb + 8*q];
#pragma unroll
            for (int j = 0; j < 6; ++j) {
                int jj = jh*6 + j;
                short8 bfr = *(const short8*)&wTs[(16*jj + lr)*72 + 32*kb + 8*q];
                acc[j] = __builtin_amdgcn_mfma_f32_16x16x32_bf16(a, bfr, acc[j], 0, 0, 0);
            }
        }
        float* qA1 = ws + OFS_QA1;
        float* kA1 = ws + OFS_KA1;
        float* vws = ws + OFS_V;
#pragma unroll
        for (int j = 0; j < 6; ++j) {
            int col = 16*(jh*6 + j) + lr;
            float* dst = (col < 64) ? qA1 : (col < 128 ? kA1 : vws);
            int c2 = col & 63;
#pragma unroll
            for (int r = 0; r < 4; ++r) {
                int grow = g0 + 16*w4 + 4*q + r;
                dst[(size_t)grow*64 + c2] = acc[j][r];
            }
        }
        return;
    }

    // ================= kNN role =================
    // 8 waves = 1 query-group (16 queries) x 8 candidate regions (512 each).
    // Sweep1: dual-chain depth-3 pipelined per-lane (min1,min2) (med3 update);
    // 256-thread reduce -> global tau = rank-8 of 16 lane-min2s (>=16 witnesses).
    // Sweep2: same pipeline + rare-path LDS-atomic compaction (E~25 / query).
    // Pass3: exact fp32 distances + bitonic top-16.
    float2* minbuf   = (float2*)smem;                          // [16*16*9]
    unsigned* surv   = (unsigned*)(smem + 18432);              // [16*KNN_CAP]
    int* scnt        = (int*)(smem + 18432 + 6144);            // [16]
    float* taubuf    = (float*)(smem + 18432 + 6144 + 64);     // [16]
    const unsigned short* apk = (const unsigned short*)(ws + OFS_APK);
    const unsigned short* bpk = (const unsigned short*)(ws + OFS_BPK);
    const int w = t >> 6, l = t & 63;             // w = candidate region (0..7)
    const int lr = l & 15, hi4 = l >> 4;
    const int g0 = bid * 16;                      // 1024 blocks -> 16384 queries
    const int b  = g0 >> 12;

    if (t < 16) scnt[t] = 0;

    // A-frag: row (query) = l&15, k = 8*(l>>4)+j  (same layout as projection)
    short8 afrag = *(const short8*)(apk + (size_t)(g0 + lr)*32 + 8*hi4);
    const unsigned short* bbase = bpk + (size_t)(b*4096 + w*512 + lr)*32 + 8*hi4;
    const floatx4 z4 = {0.f, 0.f, 0.f, 0.f};

    // ---- sweep 1: dual-chain depth-3 pipelined min1/min2 ----
    float run1[4], run2[4];
#pragma unroll
    for (int r = 0; r < 4; ++r) { run1[r] = 1e30f; run2[r] = 1e30f; }
    {
        short8 cA0 = *(const short8*)(bbase);            // chain A: tiles 0..15
        short8 cA1 = *(const short8*)(bbase + 512);
        short8 cB0 = *(const short8*)(bbase + 16*512);   // chain B: tiles 16..31
        short8 cB1 = *(const short8*)(bbase + 17*512);
#pragma unroll
        for (int g = 0; g < 16; ++g) {
            const int gn = (g + 2) & 15;     // wraps: 4 redundant loads at end
            short8 nA = *(const short8*)(bbase + gn*512);
            short8 nB = *(const short8*)(bbase + (16+gn)*512);
            floatx4 aA = __builtin_amdgcn_mfma_f32_16x16x32_bf16(afrag, cA0, z4, 0, 0, 0);
            floatx4 aB = __builtin_amdgcn_mfma_f32_16x16x32_bf16(afrag, cB0, z4, 0, 0, 0);
#pragma unroll
            for (int r = 0; r < 4; ++r) {
                // run1 <= run2 invariant -> median(a,run1,run2) == min(max(a,run1),run2)
                run2[r] = __builtin_amdgcn_fmed3f(aA[r], run1[r], run2[r]);
                run1[r] = fminf(run1[r], aA[r]);
                run2[r] = __builtin_amdgcn_fmed3f(aB[r], run1[r], run2[r]);
                run1[r] = fminf(run1[r], aB[r]);
            }
            cA0 = cA1; cA1 = nA;
            cB0 = cB1; cB1 = nB;
        }
    }
#pragma unroll
    for (int r = 0; r < 4; ++r)
        minbuf[((4*hi4 + r)*16 + lr)*9 + w] = make_float2(run1[r], run2[r]);
    __syncthreads();

    // ---- reduce: global (min1,min2) per (query, col-lane); tau = rank-8 ----
    if (t < 256) {
        int q = t >> 4, cl = t & 15;
        float m1 = 1e30f, m2 = 1e30f;
#pragma unroll
        for (int wv = 0; wv < 8; ++wv) {
            float2 p = minbuf[(q*16 + cl)*9 + wv];
            float hi = fmaxf(m1, p.x);
            m1 = fminf(m1, p.x);
            m2 = fminf(fminf(m2, p.y), hi);
        }
        float v = m2;
#pragma unroll
        for (int k = 2; k <= 16; k <<= 1) {
#pragma unroll
            for (int j = k >> 1; j > 0; j >>= 1) {
                float o = __shfl_xor(v, j, 64);
                bool up = (((cl & j) == 0) == ((cl & k) == 0));
                v = up ? fminf(v, o) : fmaxf(v, o);
            }
        }
        if (cl == 7) taubuf[q] = v + 1e-3f;       // margin >> 2*pack-error
    }
    __syncthreads();

    float tau[4];
#pragma unroll
    for (int r = 0; r < 4; ++r) tau[r] = taubuf[4*hi4 + r];

    // ---- sweep 2: same pipeline + rare-path atomic compaction ----
    const unsigned cand0 = (unsigned)(w*512 + lr);
    const int qb0 = 4*hi4;
    {
        short8 cA0 = *(const short8*)(bbase);
        short8 cA1 = *(const short8*)(bbase + 512);
        short8 cB0 = *(const short8*)(bbase + 16*512);
        short8 cB1 = *(const short8*)(bbase + 17*512);
#pragma unroll
        for (int g = 0; g < 16; ++g) {
            const int gn = (g + 2) & 15;
            short8 nA = *(const short8*)(bbase + gn*512);
            short8 nB = *(const short8*)(bbase + (16+gn)*512);
            floatx4 aA = __builtin_amdgcn_mfma_f32_16x16x32_bf16(afrag, cA0, z4, 0, 0, 0);
            floatx4 aB = __builtin_amdgcn_mfma_f32_16x16x32_bf16(afrag, cB0, z4, 0, 0, 0);
            unsigned cidA = cand0 + (unsigned)(g*16);
            unsigned cidB = cand0 + (unsigned)((16+g)*16);
#pragma unroll
            for (int r = 0; r < 4; ++r) {
                if (aA[r] <= tau[r]) {
                    int p = atomicAdd(&scnt[qb0+r], 1);
                    if (p < KNN_CAP) surv[(qb0+r)*KNN_CAP + p] = cidA;
                }
                if (aB[r] <= tau[r]) {
                    int p = atomicAdd(&scnt[qb0+r], 1);
                    if (p < KNN_CAP) surv[(qb0+r)*KNN_CAP + p] = cidB;
                }
            }
            cA0 = cA1; cA1 = nA;
            cB0 = cB1; cB1 = nB;
        }
    }
    __syncthreads();

    // ---- pass 3: exact fp32 distances for survivors, top-16 select ----
    const float4* pos4g = (const float4*)(ws + OFS_POS4);
    const float4* pos4b = pos4g + (size_t)b * N_;
    int* idx = (int*)(ws + OFS_IDX);
    int qa = 2*w, qb = 2*w + 1;                   // block-local 0..15
    int Ta = scnt[qa]; Ta = Ta < KNN_CAP ? Ta : KNN_CAP;
    int Tb = scnt[qb]; Tb = Tb < KNN_CAP ? Tb : KNN_CAP;
    const unsigned* sa = surv + qa*KNN_CAP;
    const unsigned* sb = surv + qb*KNN_CAP;
    float4 q4a = pos4g[g0 + qa];
    float4 q4b = pos4g[g0 + qb];
    unsigned long long pk0 = knn_entry(q4a, pos4b, sa, Ta, l);
    unsigned long long pk1 = knn_entry(q4b, pos4b, sb, Tb, l);
    bsortu64x2(pk0, pk1, l);
    if (Ta > 64) pk0 = knn_merge_rest1(pk0, l, q4a, pos4b, sa, Ta);
    if (Tb > 64) pk1 = knn_merge_rest1(pk1, l, q4b, pos4b, sb, Tb);
    if (l < 16) {
        idx[(size_t)(g0 + qa)*16 + l] = (int)(pk0 & 0xFFFu);
        idx[(size_t)(g0 + qb)*16 + l] = (int)(pk1 & 0xFFFu);
    }
}

// ---------------- launch 4: fused per-neighbor MLPs + softmax + agg + out ------
// R11 structure + MFMA stage F (R13).
__global__ __launch_bounds__(256) void k_attn(
    const float* __restrict__ x, const float* __restrict__ pos,
    const float* __restrict__ P1, const float* __restrict__ p1b,
    const float* __restrict__ p2b, const float* __restrict__ a2b,
    const float* __restrict__ bff, const float* __restrict__ ws,
    float* __restrict__ out) {

    __shared__ unsigned short wT[128*72];      // wcombT fragments, stride 72
    __shared__ unsigned short a2T[64*72];      // A2^T fragments, stride 72
    __shared__ unsigned short abuf[128*72];    // h1 / h2 / agg, stride 72
    __shared__ float relb[128*4];
    __shared__ int   mrow[128];

    const int t  = threadIdx.x;
    const int g0 = blockIdx.x * 8;
    const int b  = g0 >> 12;
    const float* qA1 = ws + OFS_QA1;
    const float* kA1 = ws + OFS_KA1;
    const float* vws = ws + OFS_V;
    const float* c1  = ws + OFS_C1;
    const int* idx = (const int*)(ws + OFS_IDX);
    const unsigned short* wbf = (const unsigned short*)(ws + OFS_BF16);
    const unsigned short* wfb = (const unsigned short*)(ws + OFS_WFB);

#pragma unroll
    for (int k = 0; k < 6; ++k) {
        int id  = t + 256*k;
        int row = id >> 3, cir = id & 7;
        uint4 vv = *(const uint4*)(wbf + row*64 + cir*8);
        if (row < 128) *(uint4*)&wT[row*72 + cir*8] = vv;
        else           *(uint4*)&a2T[(row-128)*72 + cir*8] = vv;
    }

    if (t < 128) {
        int p = t >> 4, k = t & 15;
        int ng = g0 + p;
        int m  = idx[(size_t)ng*16 + k];
        int mg = b * N_ + m;
        mrow[t] = mg;
        relb[t*4+0] = pos[(size_t)ng*3+0] - pos[(size_t)mg*3+0];
        relb[t*4+1] = pos[(size_t)ng*3+1] - pos[(size_t)mg*3+1];
        relb[t*4+2] = pos[(size_t)ng*3+2] - pos[(size_t)mg*3+2];
    }
    __syncthreads();

    const int w = t >> 6, l = t & 63, lr = l & 15, q = l >> 4;

    // ---- prefetch kA1 gathers + (qA1+c1) — hidden behind h1-MLP and MFMA1 ----
    float kpre[2][4][4];
    float qpre[2][4];
#pragma unroll
    for (int i = 0; i < 2; ++i) {
        int ng = g0 + 2*w + i;
#pragma unroll
        for (int j = 0; j < 4; ++j) {
            int col = 16*j + lr;
            qpre[i][j] = qA1[(size_t)ng*64 + col] + c1[col];
#pragma unroll
            for (int r = 0; r < 4; ++r) {
                int row = 32*w + 16*i + 4*q + r;
                kpre[i][j][r] = kA1[(size_t)mrow[row]*64 + col];
            }
        }
    }

    // ---- h1 = relu(rel @ P1 + p1b) -> abuf (bf16) ----
    {
        int d = t & 63, r0 = t >> 6;
        float w0 = P1[d], w1 = P1[64+d], w2 = P1[128+d], bb = p1b[d];
#pragma unroll
        for (int jj = 0; jj < 32; ++jj) {
            int r = r0 + jj*4;
            float h = fmaf(relb[r*4+2], w2, fmaf(relb[r*4+1], w1, fmaf(relb[r*4+0], w0, bb)));
            abuf[r*72 + d] = f2bf(fmaxf(h, 0.f));
        }
    }
    __syncthreads();

    // ---- MFMA1: h1[128x64] @ [P2A1 | P2] ----
    floatx4 acc1[2][8];
#pragma unroll
    for (int i = 0; i < 2; ++i)
#pragma unroll
        for (int j = 0; j < 8; ++j) acc1[i][j] = (floatx4){0.f, 0.f, 0.f, 0.f};
#pragma unroll
    for (int kb = 0; kb < 2; ++kb) {
        short8 a0 = *(const short8*)&abuf[(32*w      + lr)*72 + 32*kb + 8*q];
        short8 a1 = *(const short8*)&abuf[(32*w + 16 + lr)*72 + 32*kb + 8*q];
#pragma unroll
        for (int j = 0; j < 8; ++j) {
            short8 bfr = *(const short8*)&wT[(16*j + lr)*72 + 32*kb + 8*q];
            acc1[0][j] = __builtin_amdgcn_mfma_f32_16x16x32_bf16(a0, bfr, acc1[0][j], 0, 0, 0);
            acc1[1][j] = __builtin_amdgcn_mfma_f32_16x16x32_bf16(a1, bfr, acc1[1][j], 0, 0, 0);
        }
    }
    __syncthreads();

    // ---- epilogue1: t1 = acc + (qA1[n]+c1) - kA1[m], h2 = relu -> abuf ----
#pragma unroll
    for (int i = 0; i < 2; ++i) {
#pragma unroll
        for (int j = 0; j < 4; ++j) {
            int col = 16*j + lr;
            float qv = qpre[i][j];
#pragma unroll
            for (int r = 0; r < 4; ++r) {
                int row = 32*w + 16*i + 4*q + r;
                float t1 = acc1[i][j][r] + qv - kpre[i][j][r];
                abuf[row*72 + col] = f2bf(fmaxf(t1, 0.f));
            }
        }
    }

    // ---- prefetch v gathers + Wf^T frags — hidden behind MFMA2+softmax ----
    float vpre[2][4][4];
#pragma unroll
    for (int i = 0; i < 2; ++i)
#pragma unroll
        for (int j = 0; j < 4; ++j) {
            int col = 16*j + lr;
#pragma unroll
            for (int r = 0; r < 4; ++r) {
                int row = 32*w + 16*i + 4*q + r;
                vpre[i][j][r] = vws[(size_t)mrow[row]*64 + col];
            }
        }
    short8 wffrag[2];
#pragma unroll
    for (int kb = 0; kb < 2; ++kb)
        wffrag[kb] = *(const short8*)&wfb[(16*w + lr)*64 + 32*kb + 8*q];
    __syncthreads();

    // ---- MFMA2: h2 @ A2 ----
    floatx4 acc2[2][4];
#pragma unroll
    for (int i = 0; i < 2; ++i)
#pragma unroll
        for (int j = 0; j < 4; ++j) acc2[i][j] = (floatx4){0.f, 0.f, 0.f, 0.f};
#pragma unroll
    for (int kb = 0; kb < 2; ++kb) {
        short8 a0 = *(const short8*)&abuf[(32*w      + lr)*72 + 32*kb + 8*q];
        short8 a1 = *(const short8*)&abuf[(32*w + 16 + lr)*72 + 32*kb + 8*q];
#pragma unroll
        for (int j = 0; j < 4; ++j) {
            short8 bfr = *(const short8*)&a2T[(16*j + lr)*72 + 32*kb + 8*q];
            acc2[0][j] = __builtin_amdgcn_mfma_f32_16x16x32_bf16(a0, bfr, acc2[0][j], 0, 0, 0);
            acc2[1][j] = __builtin_amdgcn_mfma_f32_16x16x32_bf16(a1, bfr, acc2[1][j], 0, 0, 0);
        }
    }
    __syncthreads();   // all waves done reading abuf (h2) before agg overwrites

    // ---- stage E: softmax over K=16, aggregate; agg -> abuf rows 0..7 (bf16) ----
#pragma unroll
    for (int i = 0; i < 2; ++i) {
#pragma unroll
        for (int j = 0; j < 4; ++j) {
            int col = 16*j + lr;
            float a2bv = a2b[col], p2bv = p2b[col];
            float L[4];
#pragma unroll
            for (int r = 0; r < 4; ++r) L[r] = acc2[i][j][r] + a2bv;
            float mx = fmaxf(fmaxf(L[0], L[1]), fmaxf(L[2], L[3]));
            mx = fmaxf(mx, __shfl_xor(mx, 16, 64));
            mx = fmaxf(mx, __shfl_xor(mx, 32, 64));
            float ssum = 0.f, part = 0.f;
#pragma unroll
            for (int r = 0; r < 4; ++r) {
                float e = __expf((L[r] - mx) * 0.125f);
                ssum += e;
                float wv = vpre[i][j][r] + (acc1[i][4+j][r] + p2bv);
                part = fmaf(e, wv, part);
            }
            ssum += __shfl_xor(ssum, 16, 64);
            ssum += __shfl_xor(ssum, 32, 64);
            part += __shfl_xor(part, 16, 64);
            part += __shfl_xor(part, 32, 64);
            float agg = part / ssum;
            if (q == 0) abuf[(2*w + i)*72 + col] = f2bf(agg);
        }
    }
    __syncthreads();

    // ---- stage F: out = agg @ Wf + bf + x  (MFMA) ----
    {
        floatx4 accF = (floatx4){0.f, 0.f, 0.f, 0.f};
#pragma unroll
        for (int kb = 0; kb < 2; ++kb) {
            short8 afr = *(const short8*)&abuf[lr*72 + 32*kb + 8*q];
            accF = __builtin_amdgcn_mfma_f32_16x16x32_bf16(afr, wffrag[kb], accF, 0, 0, 0);
        }
        if (q < 2) {
            int col = 16*w + lr;
            float bv = bff[col];
#pragma unroll
            for (int r = 0; r < 4; ++r) {
                int g = g0 + 4*q + r;
                out[(size_t)g*64 + col] = accF[r] + bv + x[(size_t)g*64 + col];
            }
        }
    }
}

// ---------------- launch ----------------
extern "C" void kernel_launch(void* const* d_in, const int* in_sizes, int n_in,
                              void* d_out, int out_size, void* d_ws, size_t ws_size,
                              hipStream_t stream) {
    const float* x   = (const float*)d_in[0];
    const float* pos = (const float*)d_in[1];
    const float* Wq  = (const float*)d_in[2];
    const float* Wk  = (const float*)d_in[3];
    const float* Wv  = (const float*)d_in[4];
    const float* P1  = (const float*)d_in[5];
    const float* p1b = (const float*)d_in[6];
    const float* P2  = (const float*)d_in[7];
    const float* p2b = (const float*)d_in[8];
    const float* A1  = (const float*)d_in[9];
    const float* a1b = (const float*)d_in[10];
    const float* A2  = (const float*)d_in[11];
    const float* a2b = (const float*)d_in[12];
    const float* Wf  = (const float*)d_in[13];
    const float* bf  = (const float*)d_in[14];
    float* out = (float*)d_out;
    float* ws  = (float*)d_ws;

    hipLaunchKernelGGL(k_pre,   dim3(161),  dim3(256), 0, stream,
                       Wq, Wk, Wv, Wf, P2, A1, p2b, a1b, pos, ws);
    hipLaunchKernelGGL(k_knn,   dim3(1304), dim3(512), 0, stream, x, A2, ws);
    hipLaunchKernelGGL(k_attn,  dim3(2048), dim3(256), 0, stream,
                       x, pos, P1, p1b, p2b, a2b, bf, ws, out);
}